// Round 1
// baseline (1114.375 us; speedup 1.0000x reference)
//
#include <hip/hip_runtime.h>

// HierarchicalLTI2: 32-layer cascade of 64-dim LTI blocks, T=8192.
// Strategy: per-layer FIR truncation at J=32 taps (A_i spectral radius ~0.4
// => A_i^32 ~ 1e-12), each layer = GEMM via implicit im2col, f16 MFMA fp32-acc.
// Taps built exactly in fp32 via log-doubling batched 64^3 matmuls.

#define LYR 32
#define NO  64
#define TSEQ 8192
#define JT  32
#define KD  (JT*NO)              // 2048
#define PROWS (TSEQ+JT)          // 8224
#define PBUF ((size_t)PROWS*NO)  // 526336 elements (f16)

typedef _Float16 h16;
typedef _Float16 h16x8 __attribute__((ext_vector_type(8)));
typedef float    f32x4 __attribute__((ext_vector_type(4)));

// ---------------- prep1: zero pad of buffer0, cast u + C, seed K_0 ----------
__global__ __launch_bounds__(256) void prep1(
    const float* __restrict__ u, const float* __restrict__ B0,
    const float* __restrict__ Bl, const float* __restrict__ Cst,
    h16* __restrict__ pall0, h16* __restrict__ ccast, float* __restrict__ kf32)
{
    int idx = blockIdx.x*256 + threadIdx.x;
    const int n_pad = JT*NO;        // 2048
    const int n_u   = TSEQ*NO;      // 524288
    const int n_c   = LYR*NO*NO;    // 131072
    const int n_k   = LYR*NO*NO;    // 131072
    int total = n_pad + n_u + n_c + n_k;
    for (; idx < total; idx += gridDim.x*256) {
        int e = idx;
        if (e < n_pad) { pall0[e] = (h16)0.f; continue; }
        e -= n_pad;
        if (e < n_u) { pall0[n_pad + e] = (h16)u[e]; continue; }
        e -= n_u;
        if (e < n_c) { ccast[e] = (h16)Cst[e]; continue; }
        e -= n_c;
        int i = e >> 12;
        int r = e & 4095;
        // K_0 = B0 (layer 0) or B_lower[i-1]
        kf32[((size_t)i*JT)*4096 + r] = (i == 0) ? B0[r] : Bl[e - 4096];
    }
}

// ---------------- build_step: K_{h+q} = A^h * K_q ; A^{2h} = A^h * A^h ------
__global__ __launch_bounds__(256) void build_step(
    const float* __restrict__ A_stack, float* __restrict__ kf32,
    float* __restrict__ apow, int s)
{
    int h = 1 << s;
    int extra = (s < 4) ? 1 : 0;
    int slots = h + extra;
    int layer = blockIdx.x / slots;
    int q     = blockIdx.x % slots;
    const float* X = (s == 0) ? (A_stack + (size_t)layer*4096)
                              : (apow + ((size_t)layer*4 + (s-1))*4096);
    const float* Yop;
    float* Z;
    if (q < h) { Yop = kf32 + ((size_t)layer*JT + q)*4096;
                 Z   = kf32 + ((size_t)layer*JT + h + q)*4096; }
    else       { Yop = X;
                 Z   = apow + ((size_t)layer*4 + s)*4096; }

    __shared__ float lx[64*68];
    __shared__ float ly[64*68];
    int tid = threadIdx.x;
    for (int e = tid; e < 4096; e += 256) {
        int r = e >> 6, c = e & 63;
        lx[r*68 + c] = X[e];
        ly[r*68 + c] = Yop[e];
    }
    __syncthreads();
    int r0 = (tid >> 4) << 2;
    int c0 = (tid & 15) << 2;
    float acc[4][4] = {};
    for (int k = 0; k < 64; k++) {
        float a0 = lx[(r0+0)*68 + k];
        float a1 = lx[(r0+1)*68 + k];
        float a2 = lx[(r0+2)*68 + k];
        float a3 = lx[(r0+3)*68 + k];
        f32x4 bv = *(const f32x4*)&ly[k*68 + c0];
        #pragma unroll
        for (int j = 0; j < 4; j++) {
            acc[0][j] += a0*bv[j]; acc[1][j] += a1*bv[j];
            acc[2][j] += a2*bv[j]; acc[3][j] += a3*bv[j];
        }
    }
    #pragma unroll
    for (int i2 = 0; i2 < 4; i2++) {
        f32x4 o; o[0]=acc[i2][0]; o[1]=acc[i2][1]; o[2]=acc[i2][2]; o[3]=acc[i2][3];
        *(f32x4*)&Z[(size_t)(r0+i2)*64 + c0] = o;
    }
}

// ---------------- castK: Kf32[i][j][n][m] -> f16 KbufT[i][n][(J-1-j)*64+m] --
__global__ __launch_bounds__(256) void castK(const float* __restrict__ kf32,
                                             h16* __restrict__ kt)
{
    int idx = blockIdx.x*256 + threadIdx.x;
    const int total = LYR*NO*KD;     // 4,194,304
    for (; idx < total; idx += gridDim.x*256) {
        int i   = idx >> 17;         // / (64*2048)
        int rem = idx & 131071;
        int n   = rem >> 11;
        int kap = rem & 2047;
        int jp  = kap >> 6, m = kap & 63;
        int j   = JT-1-jp;
        kt[idx] = (h16)kf32[(((size_t)i*JT + j)*64 + n)*64 + m];
    }
}

// ---------------- zero_pads: zero first J rows of buffers 1..32 -------------
__global__ __launch_bounds__(256) void zero_pads(h16* __restrict__ pall)
{
    int idx = blockIdx.x*256 + threadIdx.x;
    if (idx < 32*JT*NO) {
        int b = idx >> 11;       // / 2048
        int e = idx & 2047;
        pall[(size_t)(b+1)*PBUF + e] = (h16)0.f;
    }
}

// ---------------- stage_conv: X_out = FIR(X_in, KbufT_layer) ----------------
// Grid 128 (Tt=64 rows/WG), 4 waves; wave w -> t-rows [w*16, w*16+16), n 0..63.
__global__ __launch_bounds__(256) void stage_conv(
    const h16* __restrict__ pin, h16* __restrict__ pout,
    const h16* __restrict__ kb)
{
    __shared__ h16 win[(64+JT)*72];   // stride 72 to spread banks (2-way max)
    int tid = threadIdx.x;
    size_t t0 = (size_t)blockIdx.x * 64;
    for (int e = tid; e < 96*8; e += 256) {
        int r = e >> 3, c = e & 7;
        *(int4*)&win[r*72 + c*8] = *(const int4*)&pin[(t0 + r)*64 + c*8];
    }
    __syncthreads();
    int wv = tid >> 6, lane = tid & 63, r = lane & 15, q = lane >> 4;
    const h16* arow = &win[(wv*16 + r)*72 + q*8];
    const h16* bb0 = kb + (size_t)( 0 + r)*KD + q*8;
    const h16* bb1 = kb + (size_t)(16 + r)*KD + q*8;
    const h16* bb2 = kb + (size_t)(32 + r)*KD + q*8;
    const h16* bb3 = kb + (size_t)(48 + r)*KD + q*8;
    f32x4 acc0 = {0.f,0.f,0.f,0.f}, acc1 = acc0, acc2 = acc0, acc3 = acc0;

    #define LDA(st) (*(const h16x8*)(arow + ((st)>>1)*72 + ((st)&1)*32))
    #define LDB(p,st) (*(const h16x8*)((p) + (st)*32))
    h16x8 aE=LDA(0), b0E=LDB(bb0,0), b1E=LDB(bb1,0), b2E=LDB(bb2,0), b3E=LDB(bb3,0);
    h16x8 aO=LDA(1), b0O=LDB(bb0,1), b1O=LDB(bb1,1), b2O=LDB(bb2,1), b3O=LDB(bb3,1);

    #pragma unroll
    for (int s2 = 0; s2 < 32; s2++) {
        h16x8 a = aE, c0v=b0E, c1v=b1E, c2v=b2E, c3v=b3E;
        int pf = 2*s2 + 2;
        if (pf < 64) { aE=LDA(pf); b0E=LDB(bb0,pf); b1E=LDB(bb1,pf);
                       b2E=LDB(bb2,pf); b3E=LDB(bb3,pf); }
        acc0 = __builtin_amdgcn_mfma_f32_16x16x32_f16(a, c0v, acc0, 0,0,0);
        acc1 = __builtin_amdgcn_mfma_f32_16x16x32_f16(a, c1v, acc1, 0,0,0);
        acc2 = __builtin_amdgcn_mfma_f32_16x16x32_f16(a, c2v, acc2, 0,0,0);
        acc3 = __builtin_amdgcn_mfma_f32_16x16x32_f16(a, c3v, acc3, 0,0,0);
        h16x8 a2 = aO, d0=b0O, d1=b1O, d2=b2O, d3=b3O;
        int pg = 2*s2 + 3;
        if (pg < 64) { aO=LDA(pg); b0O=LDB(bb0,pg); b1O=LDB(bb1,pg);
                       b2O=LDB(bb2,pg); b3O=LDB(bb3,pg); }
        acc0 = __builtin_amdgcn_mfma_f32_16x16x32_f16(a2, d0, acc0, 0,0,0);
        acc1 = __builtin_amdgcn_mfma_f32_16x16x32_f16(a2, d1, acc1, 0,0,0);
        acc2 = __builtin_amdgcn_mfma_f32_16x16x32_f16(a2, d2, acc2, 0,0,0);
        acc3 = __builtin_amdgcn_mfma_f32_16x16x32_f16(a2, d3, acc3, 0,0,0);
    }
    #undef LDA
    #undef LDB
    int tl = wv*16 + q*4;
    #pragma unroll
    for (int reg = 0; reg < 4; reg++) {
        size_t row = JT + t0 + tl + reg;
        pout[row*64 +  0 + r] = (h16)acc0[reg];
        pout[row*64 + 16 + r] = (h16)acc1[reg];
        pout[row*64 + 32 + r] = (h16)acc2[reg];
        pout[row*64 + 48 + r] = (h16)acc3[reg];
    }
}

// ---------------- y_final: Y = sum_i X^(i) C_i^T ----------------------------
__global__ __launch_bounds__(256) void y_final(
    const h16* __restrict__ pall, const h16* __restrict__ ccast,
    float* __restrict__ out)
{
    int tid = threadIdx.x;
    size_t t0 = (size_t)blockIdx.x * 64;
    int wv = tid >> 6, lane = tid & 63, r = lane & 15, q = lane >> 4;
    const h16* abase = pall + PBUF + (JT + t0 + wv*16 + r)*64 + q*8; // buffer 1
    const h16* bbase = ccast + (size_t)r*64 + q*8;
    f32x4 acc0 = {0.f,0.f,0.f,0.f}, acc1 = acc0, acc2 = acc0, acc3 = acc0;
    #define LDA2(st) (*(const h16x8*)(abase + (size_t)((st)>>1)*PBUF + ((st)&1)*32))
    #define LDB2(nt,st) (*(const h16x8*)(bbase + (size_t)((st)>>1)*4096 + (nt)*1024 + ((st)&1)*32))
    h16x8 aE=LDA2(0), b0E=LDB2(0,0), b1E=LDB2(1,0), b2E=LDB2(2,0), b3E=LDB2(3,0);
    h16x8 aO=LDA2(1), b0O=LDB2(0,1), b1O=LDB2(1,1), b2O=LDB2(2,1), b3O=LDB2(3,1);
    #pragma unroll
    for (int s2 = 0; s2 < 32; s2++) {
        h16x8 a = aE, c0v=b0E, c1v=b1E, c2v=b2E, c3v=b3E;
        int pf = 2*s2 + 2;
        if (pf < 64) { aE=LDA2(pf); b0E=LDB2(0,pf); b1E=LDB2(1,pf);
                       b2E=LDB2(2,pf); b3E=LDB2(3,pf); }
        acc0 = __builtin_amdgcn_mfma_f32_16x16x32_f16(a, c0v, acc0, 0,0,0);
        acc1 = __builtin_amdgcn_mfma_f32_16x16x32_f16(a, c1v, acc1, 0,0,0);
        acc2 = __builtin_amdgcn_mfma_f32_16x16x32_f16(a, c2v, acc2, 0,0,0);
        acc3 = __builtin_amdgcn_mfma_f32_16x16x32_f16(a, c3v, acc3, 0,0,0);
        h16x8 a2 = aO, d0=b0O, d1=b1O, d2=b2O, d3=b3O;
        int pg = 2*s2 + 3;
        if (pg < 64) { aO=LDA2(pg); b0O=LDB2(0,pg); b1O=LDB2(1,pg);
                       b2O=LDB2(2,pg); b3O=LDB2(3,pg); }
        acc0 = __builtin_amdgcn_mfma_f32_16x16x32_f16(a2, d0, acc0, 0,0,0);
        acc1 = __builtin_amdgcn_mfma_f32_16x16x32_f16(a2, d1, acc1, 0,0,0);
        acc2 = __builtin_amdgcn_mfma_f32_16x16x32_f16(a2, d2, acc2, 0,0,0);
        acc3 = __builtin_amdgcn_mfma_f32_16x16x32_f16(a2, d3, acc3, 0,0,0);
    }
    #undef LDA2
    #undef LDB2
    int tl = wv*16 + q*4;
    #pragma unroll
    for (int reg = 0; reg < 4; reg++) {
        size_t row = t0 + tl + reg;
        out[row*64 +  0 + r] = acc0[reg];
        out[row*64 + 16 + r] = acc1[reg];
        out[row*64 + 32 + r] = acc2[reg];
        out[row*64 + 48 + r] = acc3[reg];
    }
}

extern "C" void kernel_launch(void* const* d_in, const int* in_sizes, int n_in,
                              void* d_out, int out_size, void* d_ws, size_t ws_size,
                              hipStream_t stream)
{
    const float* u   = (const float*)d_in[0];
    const float* Ast = (const float*)d_in[1];
    const float* B0  = (const float*)d_in[2];
    const float* Bl  = (const float*)d_in[3];
    const float* Cst = (const float*)d_in[4];
    float* out = (float*)d_out;

    char* ws = (char*)d_ws;
    const size_t PBUF_BYTES = PBUF*sizeof(h16);            // 1,052,672
    // Workspace map (~45.5 MB total):
    //  [0, 33*PBUF)            : Pall - padded state buffers 0..32 (f16)
    //  [+0]                    : Ccast (f16, 256 KiB)
    //  [+262144]               : KbufT (f16, 8 MiB)
    //  [+8388608]              : Apow  (f32, 2 MiB)
    //  Kf32 (16 MiB) aliased over Pall buffers 1..17 (dead after castK).
    h16*   pall  = (h16*)ws;
    h16*   ccast = (h16*)(ws + 33*PBUF_BYTES);
    h16*   kt    = (h16*)(ws + 33*PBUF_BYTES + 262144);
    float* apow  = (float*)(ws + 33*PBUF_BYTES + 262144 + 8388608);
    float* kf32  = (float*)(ws + PBUF_BYTES);              // alias

    prep1<<<2048, 256, 0, stream>>>(u, B0, Bl, Cst, pall, ccast, kf32);
    for (int s = 0; s < 5; s++) {
        int h = 1 << s;
        int grid = 32*(h + (s < 4 ? 1 : 0));
        build_step<<<grid, 256, 0, stream>>>(Ast, kf32, apow, s);
    }
    castK<<<8192, 256, 0, stream>>>(kf32, kt);
    zero_pads<<<(32*JT*NO + 255)/256, 256, 0, stream>>>(pall);
    for (int i = 0; i < LYR; i++) {
        stage_conv<<<TSEQ/64, 256, 0, stream>>>(pall + (size_t)i*PBUF,
                                                pall + (size_t)(i+1)*PBUF,
                                                kt + (size_t)i*64*KD);
    }
    y_final<<<TSEQ/64, 256, 0, stream>>>(pall, ccast, out);
}

// Round 2
// 538.072 us; speedup vs baseline: 2.0711x; 2.0711x over previous
//
#include <hip/hip_runtime.h>

// HierarchicalLTI2: 32-layer cascade of 64-dim LTI blocks, T=8192.
// Per-layer FIR truncation at J=32 taps, each layer = GEMM (M=8192,N=64,K=2048)
// via implicit im2col, f16 MFMA fp32-acc. Taps built in fp32 by log-doubling.
// R2: split-K-across-waves stage GEMM (fixes R1's serialized-load K-loop).

#define LYR 32
#define NO  64
#define TSEQ 8192
#define JT  32
#define KD  (JT*NO)              // 2048
#define PROWS (TSEQ+JT)          // 8224
#define PBUF ((size_t)PROWS*NO)  // 526336 elements (f16)

typedef _Float16 h16;
typedef _Float16 h16x8 __attribute__((ext_vector_type(8)));
typedef float    f32x4 __attribute__((ext_vector_type(4)));

// ---------------- prep1: zero pad of buffer0, cast u + C, seed K_0 ----------
__global__ __launch_bounds__(256) void prep1(
    const float* __restrict__ u, const float* __restrict__ B0,
    const float* __restrict__ Bl, const float* __restrict__ Cst,
    h16* __restrict__ pall0, h16* __restrict__ ccast, float* __restrict__ kf32)
{
    int idx = blockIdx.x*256 + threadIdx.x;
    const int n_pad = JT*NO;        // 2048
    const int n_u   = TSEQ*NO;      // 524288
    const int n_c   = LYR*NO*NO;    // 131072
    const int n_k   = LYR*NO*NO;    // 131072
    int total = n_pad + n_u + n_c + n_k;
    for (; idx < total; idx += gridDim.x*256) {
        int e = idx;
        if (e < n_pad) { pall0[e] = (h16)0.f; continue; }
        e -= n_pad;
        if (e < n_u) { pall0[n_pad + e] = (h16)u[e]; continue; }
        e -= n_u;
        if (e < n_c) { ccast[e] = (h16)Cst[e]; continue; }
        e -= n_c;
        int i = e >> 12;
        int r = e & 4095;
        kf32[((size_t)i*JT)*4096 + r] = (i == 0) ? B0[r] : Bl[e - 4096];
    }
}

// ---------------- build_step: K_{h+q} = A^h * K_q ; A^{2h} = A^h * A^h ------
__global__ __launch_bounds__(256) void build_step(
    const float* __restrict__ A_stack, float* __restrict__ kf32,
    float* __restrict__ apow, int s)
{
    int h = 1 << s;
    int extra = (s < 4) ? 1 : 0;
    int slots = h + extra;
    int layer = blockIdx.x / slots;
    int q     = blockIdx.x % slots;
    const float* X = (s == 0) ? (A_stack + (size_t)layer*4096)
                              : (apow + ((size_t)layer*4 + (s-1))*4096);
    const float* Yop;
    float* Z;
    if (q < h) { Yop = kf32 + ((size_t)layer*JT + q)*4096;
                 Z   = kf32 + ((size_t)layer*JT + h + q)*4096; }
    else       { Yop = X;
                 Z   = apow + ((size_t)layer*4 + s)*4096; }

    __shared__ float lx[64*68];
    __shared__ float ly[64*68];
    int tid = threadIdx.x;
    for (int e = tid; e < 4096; e += 256) {
        int r = e >> 6, c = e & 63;
        lx[r*68 + c] = X[e];
        ly[r*68 + c] = Yop[e];
    }
    __syncthreads();
    int r0 = (tid >> 4) << 2;
    int c0 = (tid & 15) << 2;
    float acc[4][4] = {};
    for (int k = 0; k < 64; k++) {
        float a0 = lx[(r0+0)*68 + k];
        float a1 = lx[(r0+1)*68 + k];
        float a2 = lx[(r0+2)*68 + k];
        float a3 = lx[(r0+3)*68 + k];
        f32x4 bv = *(const f32x4*)&ly[k*68 + c0];
        #pragma unroll
        for (int j = 0; j < 4; j++) {
            acc[0][j] += a0*bv[j]; acc[1][j] += a1*bv[j];
            acc[2][j] += a2*bv[j]; acc[3][j] += a3*bv[j];
        }
    }
    #pragma unroll
    for (int i2 = 0; i2 < 4; i2++) {
        f32x4 o; o[0]=acc[i2][0]; o[1]=acc[i2][1]; o[2]=acc[i2][2]; o[3]=acc[i2][3];
        *(f32x4*)&Z[(size_t)(r0+i2)*64 + c0] = o;
    }
}

// ---------------- castK: Kf32[i][j][n][m] -> f16 KbufT[i][n][(J-1-j)*64+m] --
__global__ __launch_bounds__(256) void castK(const float* __restrict__ kf32,
                                             h16* __restrict__ kt)
{
    int idx = blockIdx.x*256 + threadIdx.x;
    const int total = LYR*NO*KD;     // 4,194,304
    for (; idx < total; idx += gridDim.x*256) {
        int i   = idx >> 17;
        int rem = idx & 131071;
        int n   = rem >> 11;
        int kap = rem & 2047;
        int jp  = kap >> 6, m = kap & 63;
        int j   = JT-1-jp;
        kt[idx] = (h16)kf32[(((size_t)i*JT + j)*64 + n)*64 + m];
    }
}

// ---------------- zero_pads: zero first J rows of buffers 1..32 -------------
__global__ __launch_bounds__(256) void zero_pads(h16* __restrict__ pall)
{
    int idx = blockIdx.x*256 + threadIdx.x;
    if (idx < 32*JT*NO) {
        int b = idx >> 11;
        int e = idx & 2047;
        pall[(size_t)(b+1)*PBUF + e] = (h16)0.f;
    }
}

// ---------------- stage_conv v2: split-K across waves -----------------------
// Grid 128 (64 t-rows/WG). Wave w owns K in [w*512, w*512+512) (16 half-steps
// of K=32), computes full 64x64 partial tile into 16 accs; cross-wave LDS
// reduction (2-copy) at the end.
__global__ __launch_bounds__(256, 1) void stage_conv(
    const h16* __restrict__ pin, h16* __restrict__ pout,
    const h16* __restrict__ kb)
{
    __shared__ __align__(16) char smraw[2*64*68*4];   // 34,816 B (union)
    h16*   win = (h16*)smraw;                         // 96x72 h16 = 13,824 B
    float* red = (float*)smraw;                       // 2 x 64x68 f32
    int tid = threadIdx.x;
    size_t t0 = (size_t)blockIdx.x * 64;
    for (int e = tid; e < 96*8; e += 256) {
        int rr = e >> 3, cc = e & 7;
        *(int4*)&win[rr*72 + cc*8] = *(const int4*)&pin[(t0 + rr)*64 + cc*8];
    }
    __syncthreads();
    int wv = tid >> 6, lane = tid & 63, r = lane & 15, q = lane >> 4;
    // A-frag (row-tile s, local half-step ls): im2col row = s*16+r + wv*8 + (ls>>1)
    const h16* abase = &win[(r + wv*8)*72 + q*8];
    // B-frag (col-tile c): kt row c*16+r, col wv*512 + ls*32 + q*8
    const h16* bbase = kb + (size_t)r*KD + wv*512 + q*8;
    #define LDA(s, ls) (*(const h16x8*)(abase + ((s)*16 + ((ls)>>1))*72 + ((ls)&1)*32))
    #define LDB(c, ls) (*(const h16x8*)(bbase + (size_t)(c)*(16*KD) + (ls)*32))
    f32x4 acc[4][4] = {};
    h16x8 aE[4], bE[4], aO[4], bO[4];
    #pragma unroll
    for (int s = 0; s < 4; s++) { aE[s]=LDA(s,0); bE[s]=LDB(s,0);
                                  aO[s]=LDA(s,1); bO[s]=LDB(s,1); }
    #pragma unroll 1
    for (int ls2 = 0; ls2 < 8; ls2++) {
        int pfE = 2*ls2 + 2; pfE = pfE > 15 ? 15 : pfE;
        int pfO = pfE + 1;   pfO = pfO > 15 ? 15 : pfO;
        h16x8 aC[4], bC[4];
        #pragma unroll
        for (int s = 0; s < 4; s++) { aC[s]=aE[s]; bC[s]=bE[s]; }
        #pragma unroll
        for (int s = 0; s < 4; s++) { aE[s]=LDA(s,pfE); bE[s]=LDB(s,pfE); }
        #pragma unroll
        for (int s = 0; s < 4; s++)
            #pragma unroll
            for (int c = 0; c < 4; c++)
                acc[s][c] = __builtin_amdgcn_mfma_f32_16x16x32_f16(aC[s], bC[c], acc[s][c], 0,0,0);
        #pragma unroll
        for (int s = 0; s < 4; s++) { aC[s]=aO[s]; bC[s]=bO[s]; }
        #pragma unroll
        for (int s = 0; s < 4; s++) { aO[s]=LDA(s,pfO); bO[s]=LDB(s,pfO); }
        #pragma unroll
        for (int s = 0; s < 4; s++)
            #pragma unroll
            for (int c = 0; c < 4; c++)
                acc[s][c] = __builtin_amdgcn_mfma_f32_16x16x32_f16(aC[s], bC[c], acc[s][c], 0,0,0);
    }
    #undef LDA
    #undef LDB
    __syncthreads();                 // win dead; red may now overwrite it
    if (wv >= 2) {                   // waves 2,3 deposit partials
        float* myred = red + (size_t)(wv-2)*(64*68);
        #pragma unroll
        for (int s = 0; s < 4; s++)
            #pragma unroll
            for (int c = 0; c < 4; c++)
                #pragma unroll
                for (int g = 0; g < 4; g++)
                    myred[(s*16 + q*4 + g)*68 + c*16 + r] = acc[s][c][g];
    }
    __syncthreads();
    if (wv < 2) {                    // waves 0,1 accumulate in place
        float* myred = red + (size_t)wv*(64*68);
        #pragma unroll
        for (int s = 0; s < 4; s++)
            #pragma unroll
            for (int c = 0; c < 4; c++)
                #pragma unroll
                for (int g = 0; g < 4; g++)
                    myred[(s*16 + q*4 + g)*68 + c*16 + r] += acc[s][c][g];
    }
    __syncthreads();
    int orow = tid >> 2, cb = (tid & 3) << 4;
    f32x4 sum[4];
    #pragma unroll
    for (int g = 0; g < 4; g++) {
        f32x4 v0 = *(const f32x4*)&red[orow*68 + cb + g*4];
        f32x4 v1 = *(const f32x4*)&red[64*68 + orow*68 + cb + g*4];
        sum[g] = v0 + v1;
    }
    h16 ov[16];
    #pragma unroll
    for (int g = 0; g < 4; g++)
        #pragma unroll
        for (int j = 0; j < 4; j++) ov[g*4+j] = (h16)sum[g][j];
    size_t obase = (JT + t0 + orow)*64 + cb;
    *(int4*)&pout[obase]     = *(int4*)&ov[0];
    *(int4*)&pout[obase + 8] = *(int4*)&ov[8];
}

// ---------------- y_final v2: Y = sum_i X^(i) C_i^T, split-K across waves ---
__global__ __launch_bounds__(256, 1) void y_final(
    const h16* __restrict__ pall, const h16* __restrict__ ccast,
    float* __restrict__ out)
{
    __shared__ __align__(16) float red[2*64*68];
    int tid = threadIdx.x;
    size_t t0 = (size_t)blockIdx.x * 64;
    int wv = tid >> 6, lane = tid & 63, r = lane & 15, q = lane >> 4;
    // wave wv owns layers i in [wv*8, wv*8+8): A from pall buffer (i+1)
    const h16* abase = pall + PBUF + (size_t)(wv*8)*PBUF + (JT + t0 + r)*64 + q*8;
    const h16* bbase = ccast + (size_t)(wv*8)*4096 + (size_t)r*64 + q*8;
    #define LDA2(s, ls) (*(const h16x8*)(abase + (size_t)((ls)>>1)*PBUF + (s)*(16*64) + ((ls)&1)*32))
    #define LDB2(c, ls) (*(const h16x8*)(bbase + (size_t)((ls)>>1)*4096 + (c)*(16*64) + ((ls)&1)*32))
    f32x4 acc[4][4] = {};
    h16x8 aE[4], bE[4], aO[4], bO[4];
    #pragma unroll
    for (int s = 0; s < 4; s++) { aE[s]=LDA2(s,0); bE[s]=LDB2(s,0);
                                  aO[s]=LDA2(s,1); bO[s]=LDB2(s,1); }
    #pragma unroll 1
    for (int ls2 = 0; ls2 < 8; ls2++) {
        int pfE = 2*ls2 + 2; pfE = pfE > 15 ? 15 : pfE;
        int pfO = pfE + 1;   pfO = pfO > 15 ? 15 : pfO;
        h16x8 aC[4], bC[4];
        #pragma unroll
        for (int s = 0; s < 4; s++) { aC[s]=aE[s]; bC[s]=bE[s]; }
        #pragma unroll
        for (int s = 0; s < 4; s++) { aE[s]=LDA2(s,pfE); bE[s]=LDB2(s,pfE); }
        #pragma unroll
        for (int s = 0; s < 4; s++)
            #pragma unroll
            for (int c = 0; c < 4; c++)
                acc[s][c] = __builtin_amdgcn_mfma_f32_16x16x32_f16(aC[s], bC[c], acc[s][c], 0,0,0);
        #pragma unroll
        for (int s = 0; s < 4; s++) { aC[s]=aO[s]; bC[s]=bO[s]; }
        #pragma unroll
        for (int s = 0; s < 4; s++) { aO[s]=LDA2(s,pfO); bO[s]=LDB2(s,pfO); }
        #pragma unroll
        for (int s = 0; s < 4; s++)
            #pragma unroll
            for (int c = 0; c < 4; c++)
                acc[s][c] = __builtin_amdgcn_mfma_f32_16x16x32_f16(aC[s], bC[c], acc[s][c], 0,0,0);
    }
    #undef LDA2
    #undef LDB2
    if (wv >= 2) {
        float* myred = red + (size_t)(wv-2)*(64*68);
        #pragma unroll
        for (int s = 0; s < 4; s++)
            #pragma unroll
            for (int c = 0; c < 4; c++)
                #pragma unroll
                for (int g = 0; g < 4; g++)
                    myred[(s*16 + q*4 + g)*68 + c*16 + r] = acc[s][c][g];
    }
    __syncthreads();
    if (wv < 2) {
        float* myred = red + (size_t)wv*(64*68);
        #pragma unroll
        for (int s = 0; s < 4; s++)
            #pragma unroll
            for (int c = 0; c < 4; c++)
                #pragma unroll
                for (int g = 0; g < 4; g++)
                    myred[(s*16 + q*4 + g)*68 + c*16 + r] += acc[s][c][g];
    }
    __syncthreads();
    int orow = tid >> 2, cb = (tid & 3) << 4;
    size_t obase = (t0 + orow)*64 + cb;
    #pragma unroll
    for (int g = 0; g < 4; g++) {
        f32x4 v0 = *(const f32x4*)&red[orow*68 + cb + g*4];
        f32x4 v1 = *(const f32x4*)&red[64*68 + orow*68 + cb + g*4];
        *(f32x4*)&out[obase + g*4] = v0 + v1;
    }
}

extern "C" void kernel_launch(void* const* d_in, const int* in_sizes, int n_in,
                              void* d_out, int out_size, void* d_ws, size_t ws_size,
                              hipStream_t stream)
{
    const float* u   = (const float*)d_in[0];
    const float* Ast = (const float*)d_in[1];
    const float* B0  = (const float*)d_in[2];
    const float* Bl  = (const float*)d_in[3];
    const float* Cst = (const float*)d_in[4];
    float* out = (float*)d_out;

    char* ws = (char*)d_ws;
    const size_t PBUF_BYTES = PBUF*sizeof(h16);            // 1,052,672
    h16*   pall  = (h16*)ws;
    h16*   ccast = (h16*)(ws + 33*PBUF_BYTES);
    h16*   kt    = (h16*)(ws + 33*PBUF_BYTES + 262144);
    float* apow  = (float*)(ws + 33*PBUF_BYTES + 262144 + 8388608);
    float* kf32  = (float*)(ws + PBUF_BYTES);              // alias (dead after castK)

    prep1<<<2048, 256, 0, stream>>>(u, B0, Bl, Cst, pall, ccast, kf32);
    for (int s = 0; s < 5; s++) {
        int h = 1 << s;
        int grid = 32*(h + (s < 4 ? 1 : 0));
        build_step<<<grid, 256, 0, stream>>>(Ast, kf32, apow, s);
    }
    castK<<<8192, 256, 0, stream>>>(kf32, kt);
    zero_pads<<<(32*JT*NO + 255)/256, 256, 0, stream>>>(pall);
    for (int i = 0; i < LYR; i++) {
        stage_conv<<<TSEQ/64, 256, 0, stream>>>(pall + (size_t)i*PBUF,
                                                pall + (size_t)(i+1)*PBUF,
                                                kt + (size_t)i*64*KD);
    }
    y_final<<<TSEQ/64, 256, 0, stream>>>(pall, ccast, out);
}

// Round 3
// 343.822 us; speedup vs baseline: 3.2411x; 1.5650x over previous
//
#include <hip/hip_runtime.h>

// HierarchicalLTI2: 32-layer cascade of 64-dim LTI blocks, T=8192.
// Per-layer FIR truncation at J=16 taps (||A^16|| ~ 0.4^16 ~ 4e-7), each layer
// = GEMM (M=8192,N=64,K=1024) via implicit im2col, f16 MFMA fp32-acc.
// R3: 256 WGs x 32-row tiles (2 blocks/CU TLP), 8-half-step split-K chains,
// depth-2 B prefetch, J=16.

#define LYR 32
#define NO  64
#define TSEQ 8192
#define JT  16
#define KD  (JT*NO)              // 1024
#define PROWS (TSEQ+JT)          // 8208
#define PBUF ((size_t)PROWS*NO)  // 525312 elements (f16)

typedef _Float16 h16;
typedef _Float16 h16x8 __attribute__((ext_vector_type(8)));
typedef float    f32x4 __attribute__((ext_vector_type(4)));

// ---- prep1: zero pads (all 33 buffers), cast u + C, seed K_0 ---------------
__global__ __launch_bounds__(256) void prep1(
    const float* __restrict__ u, const float* __restrict__ B0,
    const float* __restrict__ Bl, const float* __restrict__ Cst,
    h16* __restrict__ pall, h16* __restrict__ ccast, float* __restrict__ kf32)
{
    int idx = blockIdx.x*256 + threadIdx.x;
    const int n_pad0 = JT*NO;            // 1024
    const int n_u    = TSEQ*NO;          // 524288
    const int n_c    = LYR*NO*NO;        // 131072
    const int n_k    = LYR*NO*NO;        // 131072
    const int n_zp   = 32*JT*NO;         // 32768 (pads of buffers 1..32)
    int total = n_pad0 + n_u + n_c + n_k + n_zp;
    for (; idx < total; idx += gridDim.x*256) {
        int e = idx;
        if (e < n_pad0) { pall[e] = (h16)0.f; continue; }
        e -= n_pad0;
        if (e < n_u) { pall[n_pad0 + e] = (h16)u[e]; continue; }
        e -= n_u;
        if (e < n_c) { ccast[e] = (h16)Cst[e]; continue; }
        e -= n_c;
        if (e < n_k) {
            int i = e >> 12;
            int r = e & 4095;
            kf32[((size_t)i*JT)*4096 + r] = (i == 0) ? B0[r] : Bl[e - 4096];
            continue;
        }
        e -= n_k;
        int b = e >> 10;                 // buffer-1 index 0..31
        int off = e & 1023;
        pall[(size_t)(b+1)*PBUF + off] = (h16)0.f;
    }
}

// ---- build_step: K_{h+q} = A^h * K_q ; A^{2h} = A^h * A^h (s=0..3) ---------
__global__ __launch_bounds__(256) void build_step(
    const float* __restrict__ A_stack, float* __restrict__ kf32,
    float* __restrict__ apow, int s)
{
    int h = 1 << s;
    int extra = (s < 3) ? 1 : 0;
    int slots = h + extra;
    int layer = blockIdx.x / slots;
    int q     = blockIdx.x % slots;
    const float* X = (s == 0) ? (A_stack + (size_t)layer*4096)
                              : (apow + ((size_t)layer*4 + (s-1))*4096);
    const float* Yop;
    float* Z;
    if (q < h) { Yop = kf32 + ((size_t)layer*JT + q)*4096;
                 Z   = kf32 + ((size_t)layer*JT + h + q)*4096; }
    else       { Yop = X;
                 Z   = apow + ((size_t)layer*4 + s)*4096; }

    __shared__ float lx[64*68];
    __shared__ float ly[64*68];
    int tid = threadIdx.x;
    for (int e = tid; e < 4096; e += 256) {
        int r = e >> 6, c = e & 63;
        lx[r*68 + c] = X[e];
        ly[r*68 + c] = Yop[e];
    }
    __syncthreads();
    int r0 = (tid >> 4) << 2;
    int c0 = (tid & 15) << 2;
    float acc[4][4] = {};
    for (int k = 0; k < 64; k++) {
        float a0 = lx[(r0+0)*68 + k];
        float a1 = lx[(r0+1)*68 + k];
        float a2 = lx[(r0+2)*68 + k];
        float a3 = lx[(r0+3)*68 + k];
        f32x4 bv = *(const f32x4*)&ly[k*68 + c0];
        #pragma unroll
        for (int j = 0; j < 4; j++) {
            acc[0][j] += a0*bv[j]; acc[1][j] += a1*bv[j];
            acc[2][j] += a2*bv[j]; acc[3][j] += a3*bv[j];
        }
    }
    #pragma unroll
    for (int i2 = 0; i2 < 4; i2++) {
        f32x4 o; o[0]=acc[i2][0]; o[1]=acc[i2][1]; o[2]=acc[i2][2]; o[3]=acc[i2][3];
        *(f32x4*)&Z[(size_t)(r0+i2)*64 + c0] = o;
    }
}

// ---- castK: Kf32[i][j][n][m] -> f16 KbufT[i][n][(15-j)*64+m] ---------------
__global__ __launch_bounds__(256) void castK(const float* __restrict__ kf32,
                                             h16* __restrict__ kt)
{
    int idx = blockIdx.x*256 + threadIdx.x;
    const int total = LYR*NO*KD;     // 2,097,152
    for (; idx < total; idx += gridDim.x*256) {
        int i   = idx >> 16;
        int rem = idx & 65535;
        int n   = rem >> 10;
        int kap = rem & 1023;
        int jp  = kap >> 6, m = kap & 63;
        int j   = JT-1-jp;
        kt[idx] = (h16)kf32[(((size_t)i*JT + j)*64 + n)*64 + m];
    }
}

// ---- stage_conv v3: 32-row tiles, split-K4, 8-half-step chains -------------
__global__ __launch_bounds__(256, 2) void stage_conv(
    const h16* __restrict__ pin, h16* __restrict__ pout,
    const h16* __restrict__ kb)
{
    __shared__ __align__(16) char smraw[2*32*68*4];   // 17,408 B (union)
    h16*   win = (h16*)smraw;                         // 48 x 72 h16 = 6,912 B
    float* red = (float*)smraw;                       // 2 x 32x68 f32
    int tid = threadIdx.x;
    size_t t0 = (size_t)blockIdx.x * 32;
    for (int e = tid; e < 48*8; e += 256) {
        int rr = e >> 3, cc = e & 7;
        *(int4*)&win[rr*72 + cc*8] = *(const int4*)&pin[(t0 + rr)*64 + cc*8];
    }
    __syncthreads();
    int wv = tid >> 6, lane = tid & 63, r = lane & 15, q = lane >> 4;
    // A-frag (row-tile s, half-step ls): win row = s*16 + r + wv*4 + (ls>>1)
    const h16* abase = &win[(r + wv*4)*72 + q*8];
    // B-frag (col-tile c): kt row c*16+r, kappa = wv*256 + ls*32 + q*8
    const h16* bbase = kb + (size_t)r*KD + wv*256 + q*8;
#define LDA(s, ls) (*(const h16x8*)(abase + ((s)*16 + ((ls)>>1))*72 + ((ls)&1)*32))
#define LDB(c, ls) (*(const h16x8*)(bbase + (c)*(16*KD) + (ls)*32))
    f32x4 acc[2][4] = {};
    h16x8 a0[2], b0[4], a1[2], b1[4];
    #pragma unroll
    for (int s = 0; s < 2; s++) { a0[s]=LDA(s,0); a1[s]=LDA(s,1); }
    #pragma unroll
    for (int c = 0; c < 4; c++) { b0[c]=LDB(c,0); b1[c]=LDB(c,1); }
    #pragma unroll 1
    for (int h2 = 0; h2 < 4; h2++) {
        int pE = 2*h2 + 2; pE = pE > 7 ? 7 : pE;
        int pO = 2*h2 + 3; pO = pO > 7 ? 7 : pO;
        h16x8 ca[2], cb[4];
        #pragma unroll
        for (int s = 0; s < 2; s++) ca[s] = a0[s];
        #pragma unroll
        for (int c = 0; c < 4; c++) cb[c] = b0[c];
        #pragma unroll
        for (int s = 0; s < 2; s++) a0[s] = LDA(s, pE);
        #pragma unroll
        for (int c = 0; c < 4; c++) b0[c] = LDB(c, pE);
        #pragma unroll
        for (int s = 0; s < 2; s++)
            #pragma unroll
            for (int c = 0; c < 4; c++)
                acc[s][c] = __builtin_amdgcn_mfma_f32_16x16x32_f16(ca[s], cb[c], acc[s][c], 0,0,0);
        #pragma unroll
        for (int s = 0; s < 2; s++) ca[s] = a1[s];
        #pragma unroll
        for (int c = 0; c < 4; c++) cb[c] = b1[c];
        #pragma unroll
        for (int s = 0; s < 2; s++) a1[s] = LDA(s, pO);
        #pragma unroll
        for (int c = 0; c < 4; c++) b1[c] = LDB(c, pO);
        #pragma unroll
        for (int s = 0; s < 2; s++)
            #pragma unroll
            for (int c = 0; c < 4; c++)
                acc[s][c] = __builtin_amdgcn_mfma_f32_16x16x32_f16(ca[s], cb[c], acc[s][c], 0,0,0);
    }
#undef LDA
#undef LDB
    __syncthreads();                 // win dead; red may overwrite
    if (wv >= 2) {
        float* myred = red + (size_t)(wv-2)*(32*68);
        #pragma unroll
        for (int s = 0; s < 2; s++)
            #pragma unroll
            for (int c = 0; c < 4; c++)
                #pragma unroll
                for (int g = 0; g < 4; g++)
                    myred[(s*16 + q*4 + g)*68 + c*16 + r] = acc[s][c][g];
    }
    __syncthreads();
    if (wv < 2) {
        float* myred = red + (size_t)wv*(32*68);
        #pragma unroll
        for (int s = 0; s < 2; s++)
            #pragma unroll
            for (int c = 0; c < 4; c++)
                #pragma unroll
                for (int g = 0; g < 4; g++)
                    myred[(s*16 + q*4 + g)*68 + c*16 + r] += acc[s][c][g];
    }
    __syncthreads();
    int orow = tid >> 3, cb2 = (tid & 7) << 3;
    f32x4 u0 = *(const f32x4*)&red[orow*68 + cb2];
    f32x4 u1 = *(const f32x4*)&red[orow*68 + cb2 + 4];
    f32x4 v0 = *(const f32x4*)&red[32*68 + orow*68 + cb2];
    f32x4 v1 = *(const f32x4*)&red[32*68 + orow*68 + cb2 + 4];
    u0 += v0; u1 += v1;
    h16 ov[8];
    #pragma unroll
    for (int j = 0; j < 4; j++) { ov[j] = (h16)u0[j]; ov[4+j] = (h16)u1[j]; }
    *(int4*)&pout[(JT + t0 + orow)*64 + cb2] = *(int4*)&ov[0];
}

// ---- y_final v3: Y = sum_i X^(i) C_i^T, 32-row tiles, split-K4 -------------
__global__ __launch_bounds__(256, 2) void y_final(
    const h16* __restrict__ pall, const h16* __restrict__ ccast,
    float* __restrict__ out)
{
    __shared__ __align__(16) float red[2*32*68];
    int tid = threadIdx.x;
    size_t t0 = (size_t)blockIdx.x * 32;
    int wv = tid >> 6, lane = tid & 63, r = lane & 15, q = lane >> 4;
    // wave wv owns layers i in [wv*8, wv*8+8): 16 half-steps of 32 K-elems
    const h16* abase = pall + (size_t)(wv*8 + 1)*PBUF + (JT + t0 + r)*64 + q*8;
    const h16* bbase = ccast + (size_t)(wv*8)*4096 + (size_t)r*64 + q*8;
#define LDA2(s, ls) (*(const h16x8*)(abase + (size_t)((ls)>>1)*PBUF + (s)*(16*64) + ((ls)&1)*32))
#define LDB2(c, ls) (*(const h16x8*)(bbase + ((ls)>>1)*4096 + (c)*(16*64) + ((ls)&1)*32))
    f32x4 acc[2][4] = {};
    h16x8 a0[2], b0[4], a1[2], b1[4];
    #pragma unroll
    for (int s = 0; s < 2; s++) { a0[s]=LDA2(s,0); a1[s]=LDA2(s,1); }
    #pragma unroll
    for (int c = 0; c < 4; c++) { b0[c]=LDB2(c,0); b1[c]=LDB2(c,1); }
    #pragma unroll 1
    for (int h2 = 0; h2 < 8; h2++) {
        int pE = 2*h2 + 2; pE = pE > 15 ? 15 : pE;
        int pO = 2*h2 + 3; pO = pO > 15 ? 15 : pO;
        h16x8 ca[2], cb[4];
        #pragma unroll
        for (int s = 0; s < 2; s++) ca[s] = a0[s];
        #pragma unroll
        for (int c = 0; c < 4; c++) cb[c] = b0[c];
        #pragma unroll
        for (int s = 0; s < 2; s++) a0[s] = LDA2(s, pE);
        #pragma unroll
        for (int c = 0; c < 4; c++) b0[c] = LDB2(c, pE);
        #pragma unroll
        for (int s = 0; s < 2; s++)
            #pragma unroll
            for (int c = 0; c < 4; c++)
                acc[s][c] = __builtin_amdgcn_mfma_f32_16x16x32_f16(ca[s], cb[c], acc[s][c], 0,0,0);
        #pragma unroll
        for (int s = 0; s < 2; s++) ca[s] = a1[s];
        #pragma unroll
        for (int c = 0; c < 4; c++) cb[c] = b1[c];
        #pragma unroll
        for (int s = 0; s < 2; s++) a1[s] = LDA2(s, pO);
        #pragma unroll
        for (int c = 0; c < 4; c++) b1[c] = LDB2(c, pO);
        #pragma unroll
        for (int s = 0; s < 2; s++)
            #pragma unroll
            for (int c = 0; c < 4; c++)
                acc[s][c] = __builtin_amdgcn_mfma_f32_16x16x32_f16(ca[s], cb[c], acc[s][c], 0,0,0);
    }
#undef LDA2
#undef LDB2
    if (wv >= 2) {
        float* myred = red + (size_t)(wv-2)*(32*68);
        #pragma unroll
        for (int s = 0; s < 2; s++)
            #pragma unroll
            for (int c = 0; c < 4; c++)
                #pragma unroll
                for (int g = 0; g < 4; g++)
                    myred[(s*16 + q*4 + g)*68 + c*16 + r] = acc[s][c][g];
    }
    __syncthreads();
    if (wv < 2) {
        float* myred = red + (size_t)wv*(32*68);
        #pragma unroll
        for (int s = 0; s < 2; s++)
            #pragma unroll
            for (int c = 0; c < 4; c++)
                #pragma unroll
                for (int g = 0; g < 4; g++)
                    myred[(s*16 + q*4 + g)*68 + c*16 + r] += acc[s][c][g];
    }
    __syncthreads();
    int orow = tid >> 3, cb2 = (tid & 7) << 3;
    f32x4 u0 = *(const f32x4*)&red[orow*68 + cb2];
    f32x4 u1 = *(const f32x4*)&red[orow*68 + cb2 + 4];
    f32x4 v0 = *(const f32x4*)&red[32*68 + orow*68 + cb2];
    f32x4 v1 = *(const f32x4*)&red[32*68 + orow*68 + cb2 + 4];
    u0 += v0; u1 += v1;
    size_t obase = (t0 + orow)*64 + cb2;
    *(f32x4*)&out[obase]     = u0;
    *(f32x4*)&out[obase + 4] = u1;
}

extern "C" void kernel_launch(void* const* d_in, const int* in_sizes, int n_in,
                              void* d_out, int out_size, void* d_ws, size_t ws_size,
                              hipStream_t stream)
{
    const float* u   = (const float*)d_in[0];
    const float* Ast = (const float*)d_in[1];
    const float* B0  = (const float*)d_in[2];
    const float* Bl  = (const float*)d_in[3];
    const float* Cst = (const float*)d_in[4];
    float* out = (float*)d_out;
    (void)in_sizes; (void)n_in; (void)out_size; (void)ws_size;

    char* ws = (char*)d_ws;
    const size_t PBUF_BYTES = PBUF*sizeof(h16);            // 1,050,624
    // Workspace (~49.6 MB, no aliasing):
    h16*   pall  = (h16*)ws;                               // 33 buffers
    h16*   ccast = (h16*)(ws + 33*PBUF_BYTES);             // 256 KiB
    h16*   kt    = (h16*)(ws + 33*PBUF_BYTES + 262144);    // 4 MiB
    float* kf32  = (float*)(ws + 33*PBUF_BYTES + 262144 + 4194304);   // 8 MiB
    float* apow  = (float*)(ws + 33*PBUF_BYTES + 262144 + 4194304 + 8388608); // 2 MiB

    prep1<<<2048, 256, 0, stream>>>(u, B0, Bl, Cst, pall, ccast, kf32);
    for (int s = 0; s < 4; s++) {
        int h = 1 << s;
        int grid = 32*(h + (s < 3 ? 1 : 0));
        build_step<<<grid, 256, 0, stream>>>(Ast, kf32, apow, s);
    }
    castK<<<2048, 256, 0, stream>>>(kf32, kt);
    for (int i = 0; i < LYR; i++) {
        stage_conv<<<TSEQ/32, 256, 0, stream>>>(pall + (size_t)i*PBUF,
                                                pall + (size_t)(i+1)*PBUF,
                                                kt + (size_t)i*NO*KD);
    }
    y_final<<<TSEQ/32, 256, 0, stream>>>(pall, ccast, out);
}